// Round 10
// baseline (249.399 us; speedup 1.0000x reference)
//
#include <hip/hip_runtime.h>
#include <hip/hip_bf16.h>
#include <stdint.h>

typedef unsigned short u16;
typedef __bf16 bf16x8 __attribute__((ext_vector_type(8)));
typedef float f32x4 __attribute__((ext_vector_type(4)));

__device__ __forceinline__ u16 f2bf(float f) {
    union { float f; unsigned u; } x; x.f = f;
    unsigned u = x.u;
    u += 0x7FFFu + ((u >> 16) & 1u);   // round-to-nearest-even
    return (u16)(u >> 16);
}
__device__ __forceinline__ float bf2f(u16 h) {
    union { unsigned u; float f; } x; x.u = ((unsigned)h) << 16; return x.f;
}

// async global->LDS, 16B per lane; LDS dest is wave-uniform base + lane*16.
typedef __attribute__((address_space(1))) void gvoid;
typedef __attribute__((address_space(3))) void lvoid;
__device__ __forceinline__ void gl2lds16(const void* g, void* l) {
    __builtin_amdgcn_global_load_lds((gvoid*)g, (lvoid*)l, 16, 0, 0);
}

// ---------------------------------------------------------------------------
// Merged prep: blocks [0,2048): cast x -> bf16; [2048,2816): castT Wqkv;
// [2816,3072): castT Wproj.
// ---------------------------------------------------------------------------
__global__ __launch_bounds__(256) void prep_kernel(
    const float* __restrict__ x, u16* __restrict__ xb,
    const float* __restrict__ Wqkv, u16* __restrict__ wqkvT,
    const float* __restrict__ Wproj, u16* __restrict__ wprojT)
{
    __shared__ u16 tile[64][65];
    const int blk = blockIdx.x;
    const int tid = threadIdx.x;

    if (blk < 2048) {
        const size_t i = ((size_t)blk * 256 + tid) * 8;
        float4 a = *(const float4*)(x + i);
        float4 b = *(const float4*)(x + i + 4);
        ushort4 oa, ob;
        oa.x = f2bf(a.x); oa.y = f2bf(a.y); oa.z = f2bf(a.z); oa.w = f2bf(a.w);
        ob.x = f2bf(b.x); ob.y = f2bf(b.y); ob.z = f2bf(b.z); ob.w = f2bf(b.w);
        *(ushort4*)(xb + i) = oa;
        *(ushort4*)(xb + i + 4) = ob;
        return;
    }
    const float* in; u16* out; int rows, cols, bx, by;
    if (blk < 2816) { int t = blk - 2048; in = Wqkv;  out = wqkvT;  rows = 1024; cols = 3072; bx = t % 48; by = t / 48; }
    else            { int t = blk - 2816; in = Wproj; out = wprojT; rows = 1024; cols = 1024; bx = t % 16; by = t / 16; }
#pragma unroll
    for (int i = 0; i < 16; i++) {
        int e = i * 256 + tid;
        int r = e >> 6, c = e & 63;
        tile[r][c] = f2bf(in[(size_t)(by * 64 + r) * cols + bx * 64 + c]);
    }
    __syncthreads();
#pragma unroll
    for (int i = 0; i < 16; i++) {
        int e = i * 256 + tid;
        int r = e >> 6, c = e & 63;
        out[(size_t)(bx * 64 + r) * rows + by * 64 + c] = tile[c][r];
    }
}

// ---------------------------------------------------------------------------
// QKV GEMM v4 (unchanged): gl2lds K-loop + LDS-repacked epilogue.
// ---------------------------------------------------------------------------
__global__ __launch_bounds__(256) void gemm_qkv(
    const u16* __restrict__ A, const u16* __restrict__ Bt,
    const float* __restrict__ bias,
    u16* __restrict__ q, u16* __restrict__ ko, u16* __restrict__ vt)
{
    constexpr int K = 1024;
    __shared__ __align__(16) u16 smem[128 * 132];
    u16* sA = smem;
    u16* sB = smem + 8192;
    const int tid = threadIdx.x;
    const int wave = tid >> 6, lane = tid & 63;
    const int quad = lane >> 4, l16 = lane & 15;
    const int wm = (wave >> 1) * 64, wn = (wave & 1) * 64;
    const int m0 = blockIdx.y * 128, n0 = blockIdx.x * 128;
    const int srow = lane >> 3;
    const int scol = (lane & 7) * 8;

    f32x4 acc[4][4];
#pragma unroll
    for (int i = 0; i < 4; i++)
#pragma unroll
        for (int j = 0; j < 4; j++)
#pragma unroll
            for (int r = 0; r < 4; r++) acc[i][j][r] = 0.f;

    for (int kt = 0; kt < K; kt += 64) {
        __syncthreads();
#pragma unroll
        for (int t = 0; t < 4; t++) {
            int rb = wave * 32 + t * 8;
            gl2lds16(A  + (size_t)(m0 + rb + srow) * K + kt + scol, &sA[rb * 64]);
            gl2lds16(Bt + (size_t)(n0 + rb + srow) * K + kt + scol, &sB[rb * 64]);
        }
        __syncthreads();
#pragma unroll
        for (int kk = 0; kk < 64; kk += 32) {
            bf16x8 af[4], bfr[4];
#pragma unroll
            for (int t = 0; t < 4; t++) {
                af[t]  = *(const bf16x8*)&sA[(wm + t * 16 + l16) * 64 + kk + quad * 8];
                bfr[t] = *(const bf16x8*)&sB[(wn + t * 16 + l16) * 64 + kk + quad * 8];
            }
#pragma unroll
            for (int i = 0; i < 4; i++)
#pragma unroll
                for (int j = 0; j < 4; j++)
                    acc[i][j] = __builtin_amdgcn_mfma_f32_16x16x32_bf16(
                        af[i], bfr[j], acc[i][j], 0, 0, 0);
        }
    }

    const float QSCALE = 0.18033688011112042f;  // 0.125 * log2(e)
    const float sc = (n0 < 1024) ? QSCALE : 1.0f;
    __syncthreads();
#pragma unroll
    for (int i = 0; i < 4; i++) {
#pragma unroll
        for (int j = 0; j < 4; j++) {
            float bv = bias[n0 + wn + j * 16 + l16];
#pragma unroll
            for (int r = 0; r < 4; r++) {
                float v = (acc[i][j][r] + bv) * sc;
                smem[(wm + i * 16 + quad * 4 + r) * 132 + wn + j * 16 + l16] = f2bf(v);
            }
        }
    }
    __syncthreads();

    if (n0 < 2048) {
        u16* dst = (n0 < 1024) ? q : ko;
#pragma unroll
        for (int it = 0; it < 8; it++) {
            int c = it * 256 + tid;
            int m_l = c >> 4;
            int n8 = (c & 15) * 8;
            uint4 w = *(const uint4*)&smem[m_l * 132 + n8];
            int n = n0 + n8;
            int h = (n & 1023) >> 6, d = n & 63;
            int m = m0 + m_l;
            int b = m >> 11, t = m & 2047;
            *(uint4*)(dst + ((size_t)(b * 16 + h) * 2048 + t) * 64 + d) = w;
        }
    } else {
        int nv = n0 - 2048;
        int n_l = tid & 127, mh = tid >> 7;
        int hh = (nv >> 6) + (n_l >> 6);
        int d = n_l & 63;
        int bb = m0 >> 11, t0 = m0 & 2047;
        u16* vrow = vt + ((size_t)(bb * 16 + hh) * 64 + d) * 2048 + t0 + mh * 64;
#pragma unroll
        for (int it = 0; it < 8; it++) {
            int tch = mh * 64 + it * 8;
            union { u16 s[8]; uint4 w; } pk;
#pragma unroll
            for (int i = 0; i < 8; i++)
                pk.s[i] = smem[(tch + i) * 132 + n_l];
            *(uint4*)(vrow + it * 8) = pk.w;
        }
    }
}

// ---------------------------------------------------------------------------
// Flash attention v7 (unchanged from round 9): K-SPLIT, 1024 blocks.
// ---------------------------------------------------------------------------
__global__ __launch_bounds__(256) void attn_kernel(
    const u16* __restrict__ q, const u16* __restrict__ ko,
    const u16* __restrict__ vt,
    u16* __restrict__ op0, u16* __restrict__ op1,
    float* __restrict__ lp0, float* __restrict__ lp1)
{
    __shared__ __align__(16) u16 sQP[128 * 72];  // Q during preamble, then P
    __shared__ __align__(16) u16 sK[64 * 72];
    __shared__ __align__(16) u16 sV[64 * 72];

    const int tid = threadIdx.x;
    const int wave = tid >> 6, lane = tid & 63;
    const int quad = lane >> 4, l16 = lane & 15;

    const int lid = blockIdx.x;
    const int xcd = lid & 7, idx = lid >> 3;     // idx 0..127
    const int h = xcd * 2 + (idx & 1);
    const int b = (idx >> 1) & 1;
    const int q0 = ((idx >> 2) & 15) * 128;
    const int khalf = idx >> 6;                  // 0 or 1
    const int kbase = khalf * 1024;
    const size_t bh = (size_t)(b * 16 + h);

    const u16* qp  = q  + bh * 2048 * 64;
    const u16* kp  = ko + bh * 2048 * 64;
    const u16* vtp = vt + bh * 64 * 2048;

    const int sr0 = tid >> 3;          // 0..31
    const int sc0 = (tid & 7) * 8;
    const int sr1 = sr0 + 32;

    // stage Q tile (128 x 64)
#pragma unroll
    for (int i = 0; i < 4; i++) {
        int c = tid + i * 256;
        int r = c >> 3, cc = c & 7;
        *(uint4*)&sQP[r * 72 + cc * 8] =
            *(const uint4*)(qp + (size_t)(q0 + r) * 64 + cc * 8);
    }

    union { uint32_t u[4]; bf16x8 v; } ones;
    ones.u[0] = ones.u[1] = ones.u[2] = ones.u[3] = 0x3F803F80u;

    // prefetch tile 0 K/V of this half
    uint4 pk0 = *(const uint4*)(kp + (size_t)(kbase + sr0) * 64 + sc0);
    uint4 pk1 = *(const uint4*)(kp + (size_t)(kbase + sr1) * 64 + sc0);
    uint4 pv0 = *(const uint4*)(vtp + (size_t)sr0 * 2048 + kbase + sc0);
    uint4 pv1 = *(const uint4*)(vtp + (size_t)sr1 * 2048 + kbase + sc0);

    __syncthreads();

    // hoist Q fragments (wave rows: q0 + wave*32 .. +32)
    bf16x8 qf[2][2];
#pragma unroll
    for (int i = 0; i < 2; i++)
#pragma unroll
        for (int k2 = 0; k2 < 2; k2++)
            qf[i][k2] = *(const bf16x8*)&sQP[(wave * 32 + i * 16 + l16) * 72 + k2 * 32 + quad * 8];
    __syncthreads();   // Q consumed; sQP becomes sP

    f32x4 accO[2][4];
    f32x4 accL[2];
#pragma unroll
    for (int i = 0; i < 2; i++) {
#pragma unroll
        for (int r = 0; r < 4; r++) accL[i][r] = 0.f;
#pragma unroll
        for (int j = 0; j < 4; j++)
#pragma unroll
            for (int r = 0; r < 4; r++) accO[i][j][r] = 0.f;
    }

    for (int kt = kbase; kt < kbase + 1024; kt += 64) {
        __syncthreads();
        *(uint4*)&sK[sr0 * 72 + sc0] = pk0;
        *(uint4*)&sK[sr1 * 72 + sc0] = pk1;
        *(uint4*)&sV[sr0 * 72 + sc0] = pv0;
        *(uint4*)&sV[sr1 * 72 + sc0] = pv1;
        if (kt + 64 < kbase + 1024) {
            int nt = kt + 64;
            pk0 = *(const uint4*)(kp + (size_t)(nt + sr0) * 64 + sc0);
            pk1 = *(const uint4*)(kp + (size_t)(nt + sr1) * 64 + sc0);
            pv0 = *(const uint4*)(vtp + (size_t)sr0 * 2048 + nt + sc0);
            pv1 = *(const uint4*)(vtp + (size_t)sr1 * 2048 + nt + sc0);
        }
        __syncthreads();

        // S = Q_w (32x64) @ K_tile^T
        f32x4 S[2][4];
#pragma unroll
        for (int i = 0; i < 2; i++)
#pragma unroll
            for (int j = 0; j < 4; j++)
#pragma unroll
                for (int r = 0; r < 4; r++) S[i][j][r] = 0.f;
#pragma unroll
        for (int k2 = 0; k2 < 2; k2++) {
            int kk = k2 * 32;
#pragma unroll
            for (int j = 0; j < 4; j++) {
                bf16x8 bk = *(const bf16x8*)&sK[(j * 16 + l16) * 72 + kk + quad * 8];
                S[0][j] = __builtin_amdgcn_mfma_f32_16x16x32_bf16(qf[0][k2], bk, S[0][j], 0, 0, 0);
                S[1][j] = __builtin_amdgcn_mfma_f32_16x16x32_bf16(qf[1][k2], bk, S[1][j], 0, 0, 0);
            }
        }

        // P = exp2(S) -> bf16 LDS (truncation)
        u16* pw = &sQP[(wave * 32 + quad * 4) * 72 + l16];
#pragma unroll
        for (int i = 0; i < 2; i++)
#pragma unroll
            for (int j = 0; j < 4; j++)
#pragma unroll
                for (int r = 0; r < 4; r++) {
                    union { float f; uint32_t u; } e;
                    e.f = __builtin_amdgcn_exp2f(S[i][j][r]);
                    pw[(i * 16 + r) * 72 + j * 16] = (u16)(e.u >> 16);
                }

        // O += P @ V ; l += P @ 1
#pragma unroll
        for (int k2 = 0; k2 < 2; k2++) {
            int kk = k2 * 32;
            bf16x8 bv[4];
#pragma unroll
            for (int j = 0; j < 4; j++)
                bv[j] = *(const bf16x8*)&sV[(j * 16 + l16) * 72 + kk + quad * 8];
#pragma unroll
            for (int i = 0; i < 2; i++) {
                bf16x8 ap = *(const bf16x8*)&sQP[(wave * 32 + i * 16 + l16) * 72 + kk + quad * 8];
#pragma unroll
                for (int j = 0; j < 4; j++)
                    accO[i][j] = __builtin_amdgcn_mfma_f32_16x16x32_bf16(ap, bv[j], accO[i][j], 0, 0, 0);
                accL[i] = __builtin_amdgcn_mfma_f32_16x16x32_bf16(ap, ones.v, accL[i], 0, 0, 0);
            }
        }
    }

    // epilogue: write unnormalized O (bf16) + l (fp32) for this half
    u16* op = khalf ? op1 : op0;
    float* lp = khalf ? lp1 : lp0;
#pragma unroll
    for (int i = 0; i < 2; i++)
#pragma unroll
        for (int r = 0; r < 4; r++) {
            int t = q0 + wave * 32 + i * 16 + quad * 4 + r;
            if (l16 == 0) lp[bh * 2048 + t] = accL[i][r];
            size_t row = (size_t)b * 2048 + t;
#pragma unroll
            for (int j = 0; j < 4; j++)
                op[row * 1024 + h * 64 + j * 16 + l16] = f2bf(accO[i][j][r]);
        }
}

// ---------------------------------------------------------------------------
// Proj GEMM v3: 128m x 64n tiles, grid 512 = 2 blocks/CU (round-9 evidence:
// 1 block/CU left the barrier drain fully exposed, ~150 TF). Combine is
// FUSED into A-staging: A = (O0+O1)/(l0+l1), h = kt>>6 constant per BK=64
// iteration. B via gl2lds. fp32 out.
// ---------------------------------------------------------------------------
__global__ __launch_bounds__(256) void gemm_proj(
    const u16* __restrict__ op0, const u16* __restrict__ op1,
    const float* __restrict__ lp0, const float* __restrict__ lp1,
    const u16* __restrict__ Bt, const float* __restrict__ bias,
    float* __restrict__ out)
{
    constexpr int K = 1024;
    __shared__ __align__(16) u16 sA[128 * 64];
    __shared__ __align__(16) u16 sB[64 * 64];
    const int tid = threadIdx.x;
    const int wave = tid >> 6, lane = tid & 63;
    const int quad = lane >> 4, l16 = lane & 15;
    const int wm = (wave >> 1) * 64, wn = (wave & 1) * 32;
    const int m0 = blockIdx.y * 128, n0 = blockIdx.x * 64;
    const int srow = lane >> 3;
    const int scol = (lane & 7) * 8;

    f32x4 acc[4][2];
#pragma unroll
    for (int i = 0; i < 4; i++)
#pragma unroll
        for (int j = 0; j < 2; j++)
#pragma unroll
            for (int r = 0; r < 4; r++) acc[i][j][r] = 0.f;

    for (int kt = 0; kt < K; kt += 64) {
        __syncthreads();
        // B tile: 64 n-rows x 64 k via gl2lds
#pragma unroll
        for (int t = 0; t < 2; t++) {
            int rb = wave * 16 + t * 8;
            gl2lds16(Bt + (size_t)(n0 + rb + srow) * K + kt + scol, &sB[rb * 64]);
        }
        // A tile: combined O, normalized; h constant per iteration
        const int h = kt >> 6;
#pragma unroll
        for (int it = 0; it < 4; it++) {
            int c = tid + it * 256;
            int r = c >> 3, c8 = (c & 7) * 8;
            int m = m0 + r;
            int b = m >> 11, t2 = m & 2047;
            size_t li = (size_t)(b * 16 + h) * 2048 + t2;
            float inv = 1.f / (lp0[li] + lp1[li]);
            union { uint4 w; u16 s[8]; } a0, a1, o;
            a0.w = *(const uint4*)(op0 + (size_t)m * 1024 + kt + c8);
            a1.w = *(const uint4*)(op1 + (size_t)m * 1024 + kt + c8);
#pragma unroll
            for (int k = 0; k < 8; k++)
                o.s[k] = f2bf((bf2f(a0.s[k]) + bf2f(a1.s[k])) * inv);
            *(uint4*)&sA[r * 64 + c8] = o.w;
        }
        __syncthreads();
#pragma unroll
        for (int kk = 0; kk < 64; kk += 32) {
            bf16x8 af[4], bfr[2];
#pragma unroll
            for (int t = 0; t < 4; t++)
                af[t] = *(const bf16x8*)&sA[(wm + t * 16 + l16) * 64 + kk + quad * 8];
#pragma unroll
            for (int t = 0; t < 2; t++)
                bfr[t] = *(const bf16x8*)&sB[(wn + t * 16 + l16) * 64 + kk + quad * 8];
#pragma unroll
            for (int i = 0; i < 4; i++)
#pragma unroll
                for (int j = 0; j < 2; j++)
                    acc[i][j] = __builtin_amdgcn_mfma_f32_16x16x32_bf16(
                        af[i], bfr[j], acc[i][j], 0, 0, 0);
        }
    }

#pragma unroll
    for (int i = 0; i < 4; i++) {
#pragma unroll
        for (int j = 0; j < 2; j++) {
            int n = n0 + wn + j * 16 + l16;
            float bv = bias[n];
#pragma unroll
            for (int r = 0; r < 4; r++) {
                int m = m0 + wm + i * 16 + quad * 4 + r;
                out[(size_t)m * 1024 + n] = acc[i][j][r] + bv;
            }
        }
    }
}

// ---------------------------------------------------------------------------
extern "C" void kernel_launch(void* const* d_in, const int* in_sizes, int n_in,
                              void* d_out, int out_size, void* d_ws, size_t ws_size,
                              hipStream_t stream) {
    const float* x     = (const float*)d_in[0];
    const float* Wqkv  = (const float*)d_in[1];
    const float* bqkv  = (const float*)d_in[2];
    const float* Wproj = (const float*)d_in[3];
    const float* bproj = (const float*)d_in[4];
    float* out = (float*)d_out;
    char* ws = (char*)d_ws;

    u16* wqkvT  = (u16*)(ws);              // 6291456 B (dead after gemm_qkv)
    u16* wprojT = (u16*)(ws +  6291456);   // 2097152 B (live until gemm_proj)
    u16* xb     = (u16*)(ws +  8388608);   // 8388608 B (dead after gemm_qkv)
    u16* qb     = (u16*)(ws + 16777216);   // [B,H,N,D]
    u16* kb     = (u16*)(ws + 25165824);   // [B,H,N,D]
    u16* vtb    = (u16*)(ws + 33554432);   // [B,H,D,N]
    u16* ob     = (u16*)(ws + 41943040);   // [B,N,E]

    // partial buffers reuse dead slots during attention:
    u16*   op0 = ob;                       // half-0 unnormalized O (bf16)
    u16*   op1 = xb;                       // half-1 unnormalized O (bf16)
    float* lp0 = (float*)wqkvT;            // 65536 floats = 256 KB
    float* lp1 = (float*)(ws + 262144);    // next 256 KB (still in wqkvT slot)

    prep_kernel<<<dim3(3072), 256, 0, stream>>>(x, xb, Wqkv, wqkvT, Wproj, wprojT);
    gemm_qkv<<<dim3(24, 32), 256, 0, stream>>>(xb, wqkvT, bqkv, qb, kb, vtb);
    attn_kernel<<<dim3(1024), 256, 0, stream>>>(qb, kb, vtb, op0, op1, lp0, lp1);
    gemm_proj<<<dim3(16, 32), 256, 0, stream>>>(op0, op1, lp0, lp1, wprojT, bproj, out);
}

// Round 11
// 211.844 us; speedup vs baseline: 1.1773x; 1.1773x over previous
//
#include <hip/hip_runtime.h>
#include <hip/hip_bf16.h>
#include <stdint.h>

typedef unsigned short u16;
typedef __bf16 bf16x8 __attribute__((ext_vector_type(8)));
typedef float f32x4 __attribute__((ext_vector_type(4)));

__device__ __forceinline__ u16 f2bf(float f) {
    union { float f; unsigned u; } x; x.f = f;
    unsigned u = x.u;
    u += 0x7FFFu + ((u >> 16) & 1u);   // round-to-nearest-even
    return (u16)(u >> 16);
}
__device__ __forceinline__ float bf2f(u16 h) {
    union { unsigned u; float f; } x; x.u = ((unsigned)h) << 16; return x.f;
}

// async global->LDS, 16B per lane; LDS dest is wave-uniform base + lane*16.
typedef __attribute__((address_space(1))) void gvoid;
typedef __attribute__((address_space(3))) void lvoid;
__device__ __forceinline__ void gl2lds16(const void* g, void* l) {
    __builtin_amdgcn_global_load_lds((gvoid*)g, (lvoid*)l, 16, 0, 0);
}

// ---------------------------------------------------------------------------
// Merged prep: blocks [0,2048): cast x -> bf16; [2048,2816): castT Wqkv;
// [2816,3072): castT Wproj.
// ---------------------------------------------------------------------------
__global__ __launch_bounds__(256) void prep_kernel(
    const float* __restrict__ x, u16* __restrict__ xb,
    const float* __restrict__ Wqkv, u16* __restrict__ wqkvT,
    const float* __restrict__ Wproj, u16* __restrict__ wprojT)
{
    __shared__ u16 tile[64][65];
    const int blk = blockIdx.x;
    const int tid = threadIdx.x;

    if (blk < 2048) {
        const size_t i = ((size_t)blk * 256 + tid) * 8;
        float4 a = *(const float4*)(x + i);
        float4 b = *(const float4*)(x + i + 4);
        ushort4 oa, ob;
        oa.x = f2bf(a.x); oa.y = f2bf(a.y); oa.z = f2bf(a.z); oa.w = f2bf(a.w);
        ob.x = f2bf(b.x); ob.y = f2bf(b.y); ob.z = f2bf(b.z); ob.w = f2bf(b.w);
        *(ushort4*)(xb + i) = oa;
        *(ushort4*)(xb + i + 4) = ob;
        return;
    }
    const float* in; u16* out; int rows, cols, bx, by;
    if (blk < 2816) { int t = blk - 2048; in = Wqkv;  out = wqkvT;  rows = 1024; cols = 3072; bx = t % 48; by = t / 48; }
    else            { int t = blk - 2816; in = Wproj; out = wprojT; rows = 1024; cols = 1024; bx = t % 16; by = t / 16; }
#pragma unroll
    for (int i = 0; i < 16; i++) {
        int e = i * 256 + tid;
        int r = e >> 6, c = e & 63;
        tile[r][c] = f2bf(in[(size_t)(by * 64 + r) * cols + bx * 64 + c]);
    }
    __syncthreads();
#pragma unroll
    for (int i = 0; i < 16; i++) {
        int e = i * 256 + tid;
        int r = e >> 6, c = e & 63;
        out[(size_t)(bx * 64 + r) * rows + by * 64 + c] = tile[c][r];
    }
}

// ---------------------------------------------------------------------------
// QKV GEMM v4 (unchanged): gl2lds K-loop + LDS-repacked epilogue.
// ---------------------------------------------------------------------------
__global__ __launch_bounds__(256) void gemm_qkv(
    const u16* __restrict__ A, const u16* __restrict__ Bt,
    const float* __restrict__ bias,
    u16* __restrict__ q, u16* __restrict__ ko, u16* __restrict__ vt)
{
    constexpr int K = 1024;
    __shared__ __align__(16) u16 smem[128 * 132];
    u16* sA = smem;
    u16* sB = smem + 8192;
    const int tid = threadIdx.x;
    const int wave = tid >> 6, lane = tid & 63;
    const int quad = lane >> 4, l16 = lane & 15;
    const int wm = (wave >> 1) * 64, wn = (wave & 1) * 64;
    const int m0 = blockIdx.y * 128, n0 = blockIdx.x * 128;
    const int srow = lane >> 3;
    const int scol = (lane & 7) * 8;

    f32x4 acc[4][4];
#pragma unroll
    for (int i = 0; i < 4; i++)
#pragma unroll
        for (int j = 0; j < 4; j++)
#pragma unroll
            for (int r = 0; r < 4; r++) acc[i][j][r] = 0.f;

    for (int kt = 0; kt < K; kt += 64) {
        __syncthreads();
#pragma unroll
        for (int t = 0; t < 4; t++) {
            int rb = wave * 32 + t * 8;
            gl2lds16(A  + (size_t)(m0 + rb + srow) * K + kt + scol, &sA[rb * 64]);
            gl2lds16(Bt + (size_t)(n0 + rb + srow) * K + kt + scol, &sB[rb * 64]);
        }
        __syncthreads();
#pragma unroll
        for (int kk = 0; kk < 64; kk += 32) {
            bf16x8 af[4], bfr[4];
#pragma unroll
            for (int t = 0; t < 4; t++) {
                af[t]  = *(const bf16x8*)&sA[(wm + t * 16 + l16) * 64 + kk + quad * 8];
                bfr[t] = *(const bf16x8*)&sB[(wn + t * 16 + l16) * 64 + kk + quad * 8];
            }
#pragma unroll
            for (int i = 0; i < 4; i++)
#pragma unroll
                for (int j = 0; j < 4; j++)
                    acc[i][j] = __builtin_amdgcn_mfma_f32_16x16x32_bf16(
                        af[i], bfr[j], acc[i][j], 0, 0, 0);
        }
    }

    const float QSCALE = 0.18033688011112042f;  // 0.125 * log2(e)
    const float sc = (n0 < 1024) ? QSCALE : 1.0f;
    __syncthreads();
#pragma unroll
    for (int i = 0; i < 4; i++) {
#pragma unroll
        for (int j = 0; j < 4; j++) {
            float bv = bias[n0 + wn + j * 16 + l16];
#pragma unroll
            for (int r = 0; r < 4; r++) {
                float v = (acc[i][j][r] + bv) * sc;
                smem[(wm + i * 16 + quad * 4 + r) * 132 + wn + j * 16 + l16] = f2bf(v);
            }
        }
    }
    __syncthreads();

    if (n0 < 2048) {
        u16* dst = (n0 < 1024) ? q : ko;
#pragma unroll
        for (int it = 0; it < 8; it++) {
            int c = it * 256 + tid;
            int m_l = c >> 4;
            int n8 = (c & 15) * 8;
            uint4 w = *(const uint4*)&smem[m_l * 132 + n8];
            int n = n0 + n8;
            int h = (n & 1023) >> 6, d = n & 63;
            int m = m0 + m_l;
            int b = m >> 11, t = m & 2047;
            *(uint4*)(dst + ((size_t)(b * 16 + h) * 2048 + t) * 64 + d) = w;
        }
    } else {
        int nv = n0 - 2048;
        int n_l = tid & 127, mh = tid >> 7;
        int hh = (nv >> 6) + (n_l >> 6);
        int d = n_l & 63;
        int bb = m0 >> 11, t0 = m0 & 2047;
        u16* vrow = vt + ((size_t)(bb * 16 + hh) * 64 + d) * 2048 + t0 + mh * 64;
#pragma unroll
        for (int it = 0; it < 8; it++) {
            int tch = mh * 64 + it * 8;
            union { u16 s[8]; uint4 w; } pk;
#pragma unroll
            for (int i = 0; i < 8; i++)
                pk.s[i] = smem[(tch + i) * 132 + n_l];
            *(uint4*)(vrow + it * 8) = pk.w;
        }
    }
}

// ---------------------------------------------------------------------------
// Flash attention v7 (unchanged from round 9): K-SPLIT, 1024 blocks.
// ---------------------------------------------------------------------------
__global__ __launch_bounds__(256) void attn_kernel(
    const u16* __restrict__ q, const u16* __restrict__ ko,
    const u16* __restrict__ vt,
    u16* __restrict__ op0, u16* __restrict__ op1,
    float* __restrict__ lp0, float* __restrict__ lp1)
{
    __shared__ __align__(16) u16 sQP[128 * 72];  // Q during preamble, then P
    __shared__ __align__(16) u16 sK[64 * 72];
    __shared__ __align__(16) u16 sV[64 * 72];

    const int tid = threadIdx.x;
    const int wave = tid >> 6, lane = tid & 63;
    const int quad = lane >> 4, l16 = lane & 15;

    const int lid = blockIdx.x;
    const int xcd = lid & 7, idx = lid >> 3;     // idx 0..127
    const int h = xcd * 2 + (idx & 1);
    const int b = (idx >> 1) & 1;
    const int q0 = ((idx >> 2) & 15) * 128;
    const int khalf = idx >> 6;                  // 0 or 1
    const int kbase = khalf * 1024;
    const size_t bh = (size_t)(b * 16 + h);

    const u16* qp  = q  + bh * 2048 * 64;
    const u16* kp  = ko + bh * 2048 * 64;
    const u16* vtp = vt + bh * 64 * 2048;

    const int sr0 = tid >> 3;          // 0..31
    const int sc0 = (tid & 7) * 8;
    const int sr1 = sr0 + 32;

    // stage Q tile (128 x 64)
#pragma unroll
    for (int i = 0; i < 4; i++) {
        int c = tid + i * 256;
        int r = c >> 3, cc = c & 7;
        *(uint4*)&sQP[r * 72 + cc * 8] =
            *(const uint4*)(qp + (size_t)(q0 + r) * 64 + cc * 8);
    }

    union { uint32_t u[4]; bf16x8 v; } ones;
    ones.u[0] = ones.u[1] = ones.u[2] = ones.u[3] = 0x3F803F80u;

    // prefetch tile 0 K/V of this half
    uint4 pk0 = *(const uint4*)(kp + (size_t)(kbase + sr0) * 64 + sc0);
    uint4 pk1 = *(const uint4*)(kp + (size_t)(kbase + sr1) * 64 + sc0);
    uint4 pv0 = *(const uint4*)(vtp + (size_t)sr0 * 2048 + kbase + sc0);
    uint4 pv1 = *(const uint4*)(vtp + (size_t)sr1 * 2048 + kbase + sc0);

    __syncthreads();

    // hoist Q fragments (wave rows: q0 + wave*32 .. +32)
    bf16x8 qf[2][2];
#pragma unroll
    for (int i = 0; i < 2; i++)
#pragma unroll
        for (int k2 = 0; k2 < 2; k2++)
            qf[i][k2] = *(const bf16x8*)&sQP[(wave * 32 + i * 16 + l16) * 72 + k2 * 32 + quad * 8];
    __syncthreads();   // Q consumed; sQP becomes sP

    f32x4 accO[2][4];
    f32x4 accL[2];
#pragma unroll
    for (int i = 0; i < 2; i++) {
#pragma unroll
        for (int r = 0; r < 4; r++) accL[i][r] = 0.f;
#pragma unroll
        for (int j = 0; j < 4; j++)
#pragma unroll
            for (int r = 0; r < 4; r++) accO[i][j][r] = 0.f;
    }

    for (int kt = kbase; kt < kbase + 1024; kt += 64) {
        __syncthreads();
        *(uint4*)&sK[sr0 * 72 + sc0] = pk0;
        *(uint4*)&sK[sr1 * 72 + sc0] = pk1;
        *(uint4*)&sV[sr0 * 72 + sc0] = pv0;
        *(uint4*)&sV[sr1 * 72 + sc0] = pv1;
        if (kt + 64 < kbase + 1024) {
            int nt = kt + 64;
            pk0 = *(const uint4*)(kp + (size_t)(nt + sr0) * 64 + sc0);
            pk1 = *(const uint4*)(kp + (size_t)(nt + sr1) * 64 + sc0);
            pv0 = *(const uint4*)(vtp + (size_t)sr0 * 2048 + nt + sc0);
            pv1 = *(const uint4*)(vtp + (size_t)sr1 * 2048 + nt + sc0);
        }
        __syncthreads();

        // S = Q_w (32x64) @ K_tile^T
        f32x4 S[2][4];
#pragma unroll
        for (int i = 0; i < 2; i++)
#pragma unroll
            for (int j = 0; j < 4; j++)
#pragma unroll
                for (int r = 0; r < 4; r++) S[i][j][r] = 0.f;
#pragma unroll
        for (int k2 = 0; k2 < 2; k2++) {
            int kk = k2 * 32;
#pragma unroll
            for (int j = 0; j < 4; j++) {
                bf16x8 bk = *(const bf16x8*)&sK[(j * 16 + l16) * 72 + kk + quad * 8];
                S[0][j] = __builtin_amdgcn_mfma_f32_16x16x32_bf16(qf[0][k2], bk, S[0][j], 0, 0, 0);
                S[1][j] = __builtin_amdgcn_mfma_f32_16x16x32_bf16(qf[1][k2], bk, S[1][j], 0, 0, 0);
            }
        }

        // P = exp2(S) -> bf16 LDS (truncation)
        u16* pw = &sQP[(wave * 32 + quad * 4) * 72 + l16];
#pragma unroll
        for (int i = 0; i < 2; i++)
#pragma unroll
            for (int j = 0; j < 4; j++)
#pragma unroll
                for (int r = 0; r < 4; r++) {
                    union { float f; uint32_t u; } e;
                    e.f = __builtin_amdgcn_exp2f(S[i][j][r]);
                    pw[(i * 16 + r) * 72 + j * 16] = (u16)(e.u >> 16);
                }

        // O += P @ V ; l += P @ 1
#pragma unroll
        for (int k2 = 0; k2 < 2; k2++) {
            int kk = k2 * 32;
            bf16x8 bv[4];
#pragma unroll
            for (int j = 0; j < 4; j++)
                bv[j] = *(const bf16x8*)&sV[(j * 16 + l16) * 72 + kk + quad * 8];
#pragma unroll
            for (int i = 0; i < 2; i++) {
                bf16x8 ap = *(const bf16x8*)&sQP[(wave * 32 + i * 16 + l16) * 72 + kk + quad * 8];
#pragma unroll
                for (int j = 0; j < 4; j++)
                    accO[i][j] = __builtin_amdgcn_mfma_f32_16x16x32_bf16(ap, bv[j], accO[i][j], 0, 0, 0);
                accL[i] = __builtin_amdgcn_mfma_f32_16x16x32_bf16(ap, ones.v, accL[i], 0, 0, 0);
            }
        }
    }

    // epilogue: write unnormalized O (bf16) + l (fp32) for this half
    u16* op = khalf ? op1 : op0;
    float* lp = khalf ? lp1 : lp0;
#pragma unroll
    for (int i = 0; i < 2; i++)
#pragma unroll
        for (int r = 0; r < 4; r++) {
            int t = q0 + wave * 32 + i * 16 + quad * 4 + r;
            if (l16 == 0) lp[bh * 2048 + t] = accL[i][r];
            size_t row = (size_t)b * 2048 + t;
#pragma unroll
            for (int j = 0; j < 4; j++)
                op[row * 1024 + h * 64 + j * 16 + l16] = f2bf(accO[i][j][r]);
        }
}

// ---------------------------------------------------------------------------
// Combine (restored from round 9): ob = (O0 + O1) / (l0 + l1); ob aliases op0
// (same-element RMW is safe). One thread = 8 consecutive bf16 (same head).
// ---------------------------------------------------------------------------
__global__ __launch_bounds__(256) void combine_kernel(
    const u16* __restrict__ op0, const u16* __restrict__ op1,
    const float* __restrict__ lp0, const float* __restrict__ lp1,
    u16* __restrict__ ob)
{
    const size_t i = ((size_t)blockIdx.x * 256 + threadIdx.x) * 8;
    int m = (int)(i >> 10), e = (int)(i & 1023);
    int b = m >> 11, t = m & 2047, h = e >> 6;
    float inv = 1.f / (lp0[(size_t)(b * 16 + h) * 2048 + t] +
                       lp1[(size_t)(b * 16 + h) * 2048 + t]);
    union { uint4 w; u16 s[8]; } a, c, o;
    a.w = *(const uint4*)(op0 + i);
    c.w = *(const uint4*)(op1 + i);
#pragma unroll
    for (int k = 0; k < 8; k++)
        o.s[k] = f2bf((bf2f(a.s[k]) + bf2f(c.s[k])) * inv);
    *(uint4*)(ob + i) = o.w;
}

// ---------------------------------------------------------------------------
// Proj GEMM v4: 64m x 128n tiles, grid 512 = 2 blocks/CU (cross-block overlap
// of the gl2lds barrier drain — round-9's 1/CU left it fully exposed), XCD
// m-super-tile swizzle: per-XCD working set = A-slice 1 MB + B 2 MB, fully
// L2-resident (round-5 locality trick). Pure K-loop: A is pre-combined ob.
// Round-10 counter-evidence: fused combine cost 16x redundant A-traffic
// (FETCH 68.7 MB) + sync load on critical path — reverted.
// ---------------------------------------------------------------------------
__global__ __launch_bounds__(256) void gemm_proj(
    const u16* __restrict__ A, const u16* __restrict__ Bt,
    const float* __restrict__ bias, float* __restrict__ out)
{
    constexpr int K = 1024;
    __shared__ __align__(16) u16 sA[64 * 64];
    __shared__ __align__(16) u16 sB[128 * 64];
    const int tid = threadIdx.x;
    const int wave = tid >> 6, lane = tid & 63;
    const int quad = lane >> 4, l16 = lane & 15;
    const int wm = (wave & 1) * 32, wn = (wave >> 1) * 64;

    // XCD swizzle: 64 m-tiles x 8 n-tiles; XCD owns 8 consecutive m-tiles.
    const int lid = blockIdx.x;
    const int xcd = lid & 7, idx = lid >> 3;   // idx 0..63
    const int m0 = (xcd * 8 + (idx & 7)) * 64;
    const int n0 = (idx >> 3) * 128;

    const int srow = lane >> 3;
    const int scol = (lane & 7) * 8;

    f32x4 acc[2][4];
#pragma unroll
    for (int i = 0; i < 2; i++)
#pragma unroll
        for (int j = 0; j < 4; j++)
#pragma unroll
            for (int r = 0; r < 4; r++) acc[i][j][r] = 0.f;

    for (int kt = 0; kt < K; kt += 64) {
        __syncthreads();
#pragma unroll
        for (int t = 0; t < 2; t++) {
            int rb = wave * 16 + t * 8;
            gl2lds16(A + (size_t)(m0 + rb + srow) * K + kt + scol, &sA[rb * 64]);
        }
#pragma unroll
        for (int t = 0; t < 4; t++) {
            int rb = wave * 32 + t * 8;
            gl2lds16(Bt + (size_t)(n0 + rb + srow) * K + kt + scol, &sB[rb * 64]);
        }
        __syncthreads();
#pragma unroll
        for (int kk = 0; kk < 64; kk += 32) {
            bf16x8 af[2], bfr[4];
#pragma unroll
            for (int t = 0; t < 2; t++)
                af[t] = *(const bf16x8*)&sA[(wm + t * 16 + l16) * 64 + kk + quad * 8];
#pragma unroll
            for (int t = 0; t < 4; t++)
                bfr[t] = *(const bf16x8*)&sB[(wn + t * 16 + l16) * 64 + kk + quad * 8];
#pragma unroll
            for (int i = 0; i < 2; i++)
#pragma unroll
                for (int j = 0; j < 4; j++)
                    acc[i][j] = __builtin_amdgcn_mfma_f32_16x16x32_bf16(
                        af[i], bfr[j], acc[i][j], 0, 0, 0);
        }
    }

#pragma unroll
    for (int i = 0; i < 2; i++) {
#pragma unroll
        for (int j = 0; j < 4; j++) {
            int n = n0 + wn + j * 16 + l16;
            float bv = bias[n];
#pragma unroll
            for (int r = 0; r < 4; r++) {
                int m = m0 + wm + i * 16 + quad * 4 + r;
                out[(size_t)m * 1024 + n] = acc[i][j][r] + bv;
            }
        }
    }
}

// ---------------------------------------------------------------------------
extern "C" void kernel_launch(void* const* d_in, const int* in_sizes, int n_in,
                              void* d_out, int out_size, void* d_ws, size_t ws_size,
                              hipStream_t stream) {
    const float* x     = (const float*)d_in[0];
    const float* Wqkv  = (const float*)d_in[1];
    const float* bqkv  = (const float*)d_in[2];
    const float* Wproj = (const float*)d_in[3];
    const float* bproj = (const float*)d_in[4];
    float* out = (float*)d_out;
    char* ws = (char*)d_ws;

    u16* wqkvT  = (u16*)(ws);              // 6291456 B (dead after gemm_qkv)
    u16* wprojT = (u16*)(ws +  6291456);   // 2097152 B (live until gemm_proj)
    u16* xb     = (u16*)(ws +  8388608);   // 8388608 B (dead after gemm_qkv)
    u16* qb     = (u16*)(ws + 16777216);   // [B,H,N,D]
    u16* kb     = (u16*)(ws + 25165824);   // [B,H,N,D]
    u16* vtb    = (u16*)(ws + 33554432);   // [B,H,D,N]
    u16* ob     = (u16*)(ws + 41943040);   // [B,N,E]  (= op0, combined in place)

    // partial buffers reuse dead slots during attention:
    u16*   op0 = ob;                       // half-0 unnormalized O (bf16)
    u16*   op1 = xb;                       // half-1 unnormalized O (bf16)
    float* lp0 = (float*)wqkvT;            // 65536 floats = 256 KB
    float* lp1 = (float*)(ws + 262144);    // next 256 KB (still in wqkvT slot)

    prep_kernel<<<dim3(3072), 256, 0, stream>>>(x, xb, Wqkv, wqkvT, Wproj, wprojT);
    gemm_qkv<<<dim3(24, 32), 256, 0, stream>>>(xb, wqkvT, bqkv, qb, kb, vtb);
    attn_kernel<<<dim3(1024), 256, 0, stream>>>(qb, kb, vtb, op0, op1, lp0, lp1);
    combine_kernel<<<dim3(2048), 256, 0, stream>>>(op0, op1, lp0, lp1, ob);
    gemm_proj<<<dim3(512), 256, 0, stream>>>(ob, wprojT, bproj, out);
}